// Round 5
// baseline (718.146 us; speedup 1.0000x reference)
//
#include <hip/hip_runtime.h>
#include <hip/hip_bf16.h>
#include <math.h>

#define B_  2
#define T_  2048
#define D_  512
#define H_  8
#define HD_ 64
#define FFN_ 2048
#define VOCAB_ 256
#define BT_ (B_*T_)
#define QKVS_ 1536        // fused qkv row stride
#define NC_ 32            // chunks per (b,h), chunk size 64
#define CENT_ 4160        // floats per chunk state: 64*64 S + 64 z

typedef __attribute__((ext_vector_type(8))) short short8;
typedef __attribute__((ext_vector_type(4))) float float4v;
typedef __hip_bfloat16 bf16;

// ---------------------------------------------------------------------------
// Embedding + sinusoidal positional concat; writes fp32 x and bf16 mirror xb
// ---------------------------------------------------------------------------
__global__ __launch_bounds__(512) void embed_pos_kernel(
    const int* __restrict__ tokens, const float* __restrict__ emb,
    float* __restrict__ x, bf16* __restrict__ xb)
{
  int bt = blockIdx.x;          // b*T + t
  int t  = bt & (T_ - 1);
  int j  = threadIdx.x;
  float val;
  if (j < 256) {
    int tok = tokens[bt];
    val = emb[tok * 256 + j];
  } else {
    int jj = (j - 256) & 127;
    float f = expf(-(float)(2 * jj) * (9.210340371976184f / 256.0f));
    float arg = (float)t * f;
    val = (j < 384) ? sinf(arg) : cosf(arg);
  }
  size_t off = (size_t)bt * D_ + j;
  x[off]  = val;
  xb[off] = __float2bfloat16(val);
}

// ---------------------------------------------------------------------------
// Transpose-cast: W fp32 [K,N] (layer via blockIdx.z) -> Wt bf16 rows
// [dstOff + n][k], dest layer stride dstLayerStride elements.
// ---------------------------------------------------------------------------
__global__ __launch_bounds__(256) void transpose_cast_kernel(
    const float* __restrict__ W, bf16* __restrict__ Wt, int K, int N,
    int dstOff, long dstLayerStride)
{
  __shared__ float t[32][33];
  int n0 = blockIdx.x * 32, k0 = blockIdx.y * 32;
  const float* Wl = W + (size_t)blockIdx.z * K * N;
  bf16* Wtl = Wt + (size_t)blockIdx.z * dstLayerStride;
  int tx = threadIdx.x & 31, ty = threadIdx.x >> 5;  // ty 0..7
#pragma unroll
  for (int r = 0; r < 4; ++r)
    t[ty + 8 * r][tx] = Wl[(size_t)(k0 + ty + 8 * r) * N + n0 + tx];
  __syncthreads();
#pragma unroll
  for (int r = 0; r < 4; ++r)
    Wtl[(size_t)(dstOff + n0 + ty + 8 * r) * K + k0 + tx] =
        __float2bfloat16(t[tx][ty + 8 * r]);
}

// ---------------------------------------------------------------------------
// Concat qkv biases: bqkv[l][1536] = [bq[l] | bk[l] | bv[l]]
// ---------------------------------------------------------------------------
__global__ __launch_bounds__(256) void bias_cat_kernel(
    const float* __restrict__ bq, const float* __restrict__ bk,
    const float* __restrict__ bv, float* __restrict__ bqkv)
{
  int i = blockIdx.x * 256 + threadIdx.x;      // 0..3071
  int l = i / QKVS_, j = i % QKVS_;
  float v = (j < 512) ? bq[l * 512 + j]
          : (j < 1024) ? bk[l * 512 + j - 512]
                       : bv[l * 512 + j - 1024];
  bqkv[i] = v;
}

// ---------------------------------------------------------------------------
// bf16 MFMA GEMM: C[M,N] = act(A[M,K] @ Bt[N,K]^T + bias[N])
// 128x128 tile, BK=32, 256 threads = 4 waves (2x2), each wave 64x64.
// LDS row stride 40 shorts (80 B): bank = (20*row + dword) % 32 -> 2-way
// max on both ds_write_b128 and ds_read_b128 (free; was 8-way at stride 32).
// mode 0: store fp32. mode 1: gelu, store bf16.
// ---------------------------------------------------------------------------
#define RS_ 40
__global__ __launch_bounds__(256) void gemm_mfma(
    const bf16* __restrict__ A, const bf16* __restrict__ Bt,
    const float* __restrict__ bias, void* __restrict__ Cout,
    int M, int N, int K, int mode)
{
  __shared__ short Sl[256 * RS_];   // A rows then B rows, k contiguous
  short* Al = Sl;
  short* Bl = Sl + 128 * RS_;
  int tid = threadIdx.x;
  int lane = tid & 63, w = tid >> 6;
  int row0 = blockIdx.y * 128, col0 = blockIdx.x * 128;
  int wm = (w >> 1) * 64, wn = (w & 1) * 64;
  int quad = lane >> 4, l16 = lane & 15;
  float4v acc[4][4] = {};

  // staging: thread owns 16B at combined row (p*64 + tid>>2), k-off (tid&3)*8
  int sr = tid >> 2;
  int sk = (tid & 3) * 8;
  const short* gp[4];
#pragma unroll
  for (int p = 0; p < 4; ++p) {
    int cr = p * 64 + sr;
    gp[p] = (cr < 128) ? (const short*)A + (size_t)(row0 + cr) * K + sk
                       : (const short*)Bt + (size_t)(col0 + (cr - 128)) * K + sk;
  }
  uint4 st[4];
#pragma unroll
  for (int p = 0; p < 4; ++p) st[p] = *(const uint4*)gp[p];

  const int kr = K >> 5;
  for (int kt = 0; kt < kr; ++kt) {
    __syncthreads();               // previous compute done
#pragma unroll
    for (int p = 0; p < 4; ++p)
      *(uint4*)&Sl[(p * 64 + sr) * RS_ + sk] = st[p];
    __syncthreads();
    if (kt + 1 < kr) {             // prefetch next tile (overlaps compute)
#pragma unroll
      for (int p = 0; p < 4; ++p)
        st[p] = *(const uint4*)(gp[p] + (kt + 1) * 32);
    }
    short8 af[4], bfr[4];
#pragma unroll
    for (int mi = 0; mi < 4; ++mi)
      af[mi] = *(const short8*)&Al[(wm + mi * 16 + l16) * RS_ + quad * 8];
#pragma unroll
    for (int ni = 0; ni < 4; ++ni)
      bfr[ni] = *(const short8*)&Bl[(wn + ni * 16 + l16) * RS_ + quad * 8];
#pragma unroll
    for (int mi = 0; mi < 4; ++mi)
#pragma unroll
      for (int ni = 0; ni < 4; ++ni)
        acc[mi][ni] = __builtin_amdgcn_mfma_f32_16x16x32_bf16(
            af[mi], bfr[ni], acc[mi][ni], 0, 0, 0);
  }

  // epilogue: C[i][j], i = row0+wm+mi*16+quad*4+r, j = col0+wn+ni*16+l16
#pragma unroll
  for (int mi = 0; mi < 4; ++mi) {
#pragma unroll
    for (int ni = 0; ni < 4; ++ni) {
      int j = col0 + wn + ni * 16 + l16;
      float bj = bias[j];
#pragma unroll
      for (int r = 0; r < 4; ++r) {
        int i = row0 + wm + mi * 16 + quad * 4 + r;
        float v = acc[mi][ni][r] + bj;
        if (mode == 1) {
          v = 0.5f * v * (1.0f + erff(v * 0.7071067811865475f));
          ((bf16*)Cout)[(size_t)i * N + j] = __float2bfloat16(v);
        } else {
          ((float*)Cout)[(size_t)i * N + j] = v;
        }
      }
    }
  }
}

// ---------------------------------------------------------------------------
// FAVOR+ feature map, in place on fused qkv buffer (q and k halves).
// One wave per (bth, side) unit; 4 waves per block.
// ---------------------------------------------------------------------------
__global__ __launch_bounds__(256) void favor_kernel(
    float* __restrict__ qkv, const float* __restrict__ rfs)
{
  int u = blockIdx.x * 4 + (threadIdx.x >> 6);  // 0 .. 2*BT*H-1
  int m = threadIdx.x & 63;
  int bth = u >> 1;
  int side = u & 1;                 // 0: q (col 0), 1: k (col 512)
  int h = bth & 7;
  int bt = bth >> 3;
  __shared__ float xps[4][64];
  float* xp = xps[threadIdx.x >> 6];
  size_t off = (size_t)bt * QKVS_ + side * 512 + h * 64;
  xp[m] = qkv[off + m] * 0.35355339059327373f;   // 64^-0.25
  __syncthreads();
  const float* R = rfs + h * 64 * 64;
  float sq = 0.f, dot = 0.f;
#pragma unroll 8
  for (int dd = 0; dd < 64; ++dd) {
    float xv = xp[dd];
    sq  += xv * xv;
    dot += xv * R[dd * 64 + m];
  }
  qkv[off + m] = __expf(dot - 0.5f * sq);
}

// ---------------------------------------------------------------------------
// Pass 1: per-chunk sums (chunks 0..30 per bh), from fused qkv buffer
// ---------------------------------------------------------------------------
__global__ __launch_bounds__(256) void chunk_sum_kernel(
    const float* __restrict__ qkv, float* __restrict__ buf)
{
  int bh = blockIdx.x / 31;
  int c  = blockIdx.x % 31;
  int b = bh >> 3, h = bh & 7;
  __shared__ float Ks[64][68], Vs[64][68];
  int tid = threadIdx.x;
  int d = tid & 63, g = tid >> 6;
  for (int t4 = 0; t4 < 64; t4 += 4) {
    int t = t4 + g;
    size_t off = ((size_t)(b * T_ + c * 64 + t) * QKVS_) + h * 64 + d;
    Ks[t][d] = qkv[off + 512];
    Vs[t][d] = qkv[off + 1024];
  }
  __syncthreads();
  float acc[16];
#pragma unroll
  for (int i = 0; i < 16; ++i) acc[i] = 0.f;
  for (int t = 0; t < 64; ++t) {
    float vv = Vs[t][d];
#pragma unroll
    for (int i = 0; i < 16; ++i) acc[i] += Ks[t][g * 16 + i] * vv;
  }
  size_t bo = (size_t)(bh * 31 + c) * CENT_;
#pragma unroll
  for (int i = 0; i < 16; ++i) buf[bo + (size_t)(g * 16 + i) * 64 + d] = acc[i];
  if (tid < 64) {
    float zz = 0.f;
    for (int t = 0; t < 64; ++t) zz += Ks[t][tid];
    buf[bo + 4096 + tid] = zz;
  }
}

// ---------------------------------------------------------------------------
// Pass 2: inclusive scan over 31 chunk states per (b,h)
// ---------------------------------------------------------------------------
__global__ __launch_bounds__(256) void chunk_prefix_kernel(float* __restrict__ buf)
{
  int bh = blockIdx.x / 17;
  int grp = blockIdx.x % 17;
  int e = grp * 256 + threadIdx.x;
  if (e >= CENT_) return;
  size_t base = (size_t)bh * 31 * CENT_ + e;
  float run = 0.f;
  for (int c = 0; c < 31; ++c) {
    run += buf[base + (size_t)c * CENT_];
    buf[base + (size_t)c * CENT_] = run;
  }
}

// ---------------------------------------------------------------------------
// Pass 3: per-chunk attention (pad 65: lane-indexed rows -> conflict-free)
// ---------------------------------------------------------------------------
__global__ __launch_bounds__(256) void chunk_attn_kernel(
    const float* __restrict__ qkv, const float* __restrict__ buf,
    float* __restrict__ out)
{
  int bh = blockIdx.x >> 5;
  int c  = blockIdx.x & 31;
  int b = bh >> 3, h = bh & 7;
  __shared__ float Qs[64][65], Ks[64][65], Vs[64][65];  // Ks reused for A
  __shared__ float den[64];
  int tid = threadIdx.x;
  int d = tid & 63, g = tid >> 6;
  for (int t4 = 0; t4 < 64; t4 += 4) {
    int t = t4 + g;
    size_t off = ((size_t)(b * T_ + c * 64 + t) * QKVS_) + h * 64 + d;
    Qs[t][d] = qkv[off];
    Ks[t][d] = qkv[off + 512];
    Vs[t][d] = qkv[off + 1024];
  }
  __syncthreads();
  float a[16];
  {
    int i = d;
#pragma unroll
    for (int jj = 0; jj < 16; ++jj) a[jj] = 0.f;
    for (int m = 0; m < 64; ++m) {
      float qv = Qs[i][m];
#pragma unroll
      for (int jj = 0; jj < 16; ++jj) a[jj] += qv * Ks[g * 16 + jj][m];
    }
  }
  __syncthreads();
  {
    int i = d;
#pragma unroll
    for (int jj = 0; jj < 16; ++jj) {
      int j = g * 16 + jj;
      Ks[i][j] = (j <= i) ? a[jj] : 0.f;
    }
  }
  __syncthreads();
  const float* S0 = buf + (size_t)(bh * 31 + (c - 1)) * CENT_;  // valid if c>0
  if (tid < 64) {
    int i = tid;
    float dn = 0.f;
    for (int j = 0; j < 64; ++j) dn += Ks[i][j];
    if (c > 0) {
      const float* z0 = S0 + 4096;
      for (int m = 0; m < 64; ++m) dn += Qs[i][m] * z0[m];
    }
    den[i] = dn;
  }
  float acc[16];
#pragma unroll
  for (int ii = 0; ii < 16; ++ii) acc[ii] = 0.f;
  for (int j = 0; j < 64; ++j) {
    float vv = Vs[j][d];
#pragma unroll
    for (int ii = 0; ii < 16; ++ii) acc[ii] += Ks[g * 16 + ii][j] * vv;
  }
  if (c > 0) {
    for (int m = 0; m < 64; ++m) {
      float s0 = S0[(size_t)m * 64 + d];
#pragma unroll
      for (int ii = 0; ii < 16; ++ii) acc[ii] += Qs[g * 16 + ii][m] * s0;
    }
  }
  __syncthreads();
#pragma unroll
  for (int ii = 0; ii < 16; ++ii) {
    int i = g * 16 + ii;
    size_t off = ((size_t)(b * T_ + c * 64 + i) * D_) + h * 64 + d;
    out[off] = acc[ii] / (den[i] + 1e-16f);
  }
}

// ---------------------------------------------------------------------------
// x[row,:] += LayerNorm(a[row,:]) * g + b ; also writes bf16 mirror xb
// ---------------------------------------------------------------------------
__global__ __launch_bounds__(256) void ln_add_kernel(
    float* __restrict__ x, bf16* __restrict__ xb, const float* __restrict__ a,
    const float* __restrict__ g, const float* __restrict__ bta)
{
  int row = blockIdx.x;
  int tid = threadIdx.x;
  const float* ar = a + (size_t)row * D_;
  float v0 = ar[tid], v1 = ar[tid + 256];
  __shared__ float red[4];
  float w = v0 + v1;
  for (int o = 32; o > 0; o >>= 1) w += __shfl_down(w, o, 64);
  if ((tid & 63) == 0) red[tid >> 6] = w;
  __syncthreads();
  float mu = (red[0] + red[1] + red[2] + red[3]) * (1.f / 512.f);
  float d0 = v0 - mu, d1 = v1 - mu;
  __syncthreads();
  w = d0 * d0 + d1 * d1;
  for (int o = 32; o > 0; o >>= 1) w += __shfl_down(w, o, 64);
  if ((tid & 63) == 0) red[tid >> 6] = w;
  __syncthreads();
  float var = (red[0] + red[1] + red[2] + red[3]) * (1.f / 512.f);
  float rs = rsqrtf(var + 1e-5f);
  size_t xoff = (size_t)row * D_;
  float n0 = x[xoff + tid]       + d0 * rs * g[tid]       + bta[tid];
  float n1 = x[xoff + tid + 256] + d1 * rs * g[tid + 256] + bta[tid + 256];
  x[xoff + tid]        = n0;
  x[xoff + tid + 256]  = n1;
  xb[xoff + tid]       = __float2bfloat16(n0);
  xb[xoff + tid + 256] = __float2bfloat16(n1);
}

// ---------------------------------------------------------------------------
extern "C" void kernel_launch(void* const* d_in, const int* in_sizes, int n_in,
                              void* d_out, int out_size, void* d_ws, size_t ws_size,
                              hipStream_t stream) {
  const int*   tokens = (const int*)  d_in[0];
  const float* emb    = (const float*)d_in[1];
  const float* Wq     = (const float*)d_in[2];
  const float* bq     = (const float*)d_in[3];
  const float* Wk     = (const float*)d_in[4];
  const float* bk     = (const float*)d_in[5];
  const float* Wv     = (const float*)d_in[6];
  const float* bv     = (const float*)d_in[7];
  const float* rfs    = (const float*)d_in[8];
  const float* ln1g   = (const float*)d_in[9];
  const float* ln1b   = (const float*)d_in[10];
  const float* ln2g   = (const float*)d_in[11];
  const float* ln2b   = (const float*)d_in[12];
  const float* WU     = (const float*)d_in[13];
  const float* bU     = (const float*)d_in[14];
  const float* WV     = (const float*)d_in[15];
  const float* bV     = (const float*)d_in[16];
  const float* Wout   = (const float*)d_in[17];
  const float* bout   = (const float*)d_in[18];
  float* out = (float*)d_out;

  const size_t R = (size_t)BT_ * D_;          // 2,097,152 floats (8 MB)
  float* ws  = (float*)d_ws;
  float* x   = ws;                            // R
  float* ab  = ws + R;                        // R
  float* qkv = ws + 2 * R;                    // 3R  [BT][1536]
  float* sb  = ws + 5 * R;                    // chunk states (uses <R)
  bf16*  xb  = (bf16*)(ws + 6 * R);           // R elems
  bf16*  hb  = (bf16*)(ws + 6 * R + R / 2);   // BT*FFN elems (2R floats)
  bf16*  WqkvT = (bf16*)(ws + 6 * R + R / 2 + 2 * R);   // [L][1536][512]
  bf16*  WUT   = WqkvT + (size_t)2 * QKVS_ * D_;        // [L][FFN][D]
  bf16*  WVT   = WUT   + (size_t)2 * D_ * FFN_;         // [L][D][FFN]
  bf16*  WoutT = WVT   + (size_t)2 * FFN_ * D_;         // [VOCAB][D]
  float* bqkv  = (float*)(WoutT + (size_t)VOCAB_ * D_); // [L][1536]

  // ---- weight prep ----
  transpose_cast_kernel<<<dim3(16, 16, 2), 256, 0, stream>>>(Wq, WqkvT, D_, D_, 0,    (long)QKVS_ * D_);
  transpose_cast_kernel<<<dim3(16, 16, 2), 256, 0, stream>>>(Wk, WqkvT, D_, D_, 512,  (long)QKVS_ * D_);
  transpose_cast_kernel<<<dim3(16, 16, 2), 256, 0, stream>>>(Wv, WqkvT, D_, D_, 1024, (long)QKVS_ * D_);
  transpose_cast_kernel<<<dim3(64, 16, 2), 256, 0, stream>>>(WU, WUT, D_, FFN_, 0, (long)FFN_ * D_);
  transpose_cast_kernel<<<dim3(16, 64, 2), 256, 0, stream>>>(WV, WVT, FFN_, D_, 0, (long)D_ * FFN_);
  transpose_cast_kernel<<<dim3(8, 16, 1),  256, 0, stream>>>(Wout, WoutT, D_, VOCAB_, 0, 0);
  bias_cat_kernel<<<12, 256, 0, stream>>>(bq, bk, bv, bqkv);

  embed_pos_kernel<<<BT_, 512, 0, stream>>>(tokens, emb, x, xb);

  for (int l = 0; l < 2; ++l) {
    // fused QKV: [BT,512] x [512,1536]
    gemm_mfma<<<dim3(QKVS_/128, BT_/128), 256, 0, stream>>>(
        xb, WqkvT + (size_t)l * QKVS_ * D_, bqkv + l * QKVS_, qkv, BT_, QKVS_, D_, 0);

    const float* rfl = rfs + (size_t)l * H_ * 64 * 64;
    favor_kernel<<<2 * BT_ * H_ / 4, 256, 0, stream>>>(qkv, rfl);

    chunk_sum_kernel<<<16 * 31, 256, 0, stream>>>(qkv, sb);
    chunk_prefix_kernel<<<16 * 17, 256, 0, stream>>>(sb);
    chunk_attn_kernel<<<16 * NC_, 256, 0, stream>>>(qkv, sb, ab);

    ln_add_kernel<<<BT_, 256, 0, stream>>>(x, xb, ab, ln1g + l*D_, ln1b + l*D_);

    gemm_mfma<<<dim3(FFN_/128, BT_/128), 256, 0, stream>>>(
        xb, WUT + (size_t)l * D_ * FFN_, bU + l * FFN_, hb, BT_, FFN_, D_, 1);
    gemm_mfma<<<dim3(D_/128, BT_/128), 256, 0, stream>>>(
        hb, WVT + (size_t)l * FFN_ * D_, bV + l * D_, ab, BT_, D_, FFN_, 0);

    ln_add_kernel<<<BT_, 256, 0, stream>>>(x, xb, ab, ln2g + l*D_, ln2b + l*D_);
  }

  gemm_mfma<<<dim3(VOCAB_/128, BT_/128), 256, 0, stream>>>(
      xb, WoutT, bout, out, BT_, VOCAB_, D_, 0);
}

// Round 6
// 517.276 us; speedup vs baseline: 1.3883x; 1.3883x over previous
//
#include <hip/hip_runtime.h>
#include <hip/hip_bf16.h>
#include <math.h>

#define B_  2
#define T_  2048
#define D_  512
#define H_  8
#define HD_ 64
#define FFN_ 2048
#define VOCAB_ 256
#define BT_ (B_*T_)
#define NC_ 32            // chunks per (b,h), chunk size 64
#define CENT_ 4160        // floats per chunk state: 64*64 S + 64 z

typedef __attribute__((ext_vector_type(8))) short short8;
typedef __attribute__((ext_vector_type(4))) float float4v;
typedef __hip_bfloat16 bf16;

// ---------------------------------------------------------------------------
// Embedding + sinusoidal positional concat; writes fp32 x and bf16 mirror xb
// ---------------------------------------------------------------------------
__global__ __launch_bounds__(512) void embed_pos_kernel(
    const int* __restrict__ tokens, const float* __restrict__ emb,
    float* __restrict__ x, bf16* __restrict__ xb)
{
  int bt = blockIdx.x;          // b*T + t
  int t  = bt & (T_ - 1);
  int j  = threadIdx.x;
  float val;
  if (j < 256) {
    int tok = tokens[bt];
    val = emb[tok * 256 + j];
  } else {
    int jj = (j - 256) & 127;
    float f = expf(-(float)(2 * jj) * (9.210340371976184f / 256.0f));
    float arg = (float)t * f;
    val = (j < 384) ? sinf(arg) : cosf(arg);
  }
  size_t off = (size_t)bt * D_ + j;
  x[off]  = val;
  xb[off] = __float2bfloat16(val);
}

// ---------------------------------------------------------------------------
// Transpose-cast: W fp32 [K,N] (layer slice via blockIdx.z) -> Wt bf16 [N,K]
// ---------------------------------------------------------------------------
__global__ __launch_bounds__(256) void transpose_cast_kernel(
    const float* __restrict__ W, bf16* __restrict__ Wt, int K, int N)
{
  __shared__ float t[32][33];
  int n0 = blockIdx.x * 32, k0 = blockIdx.y * 32;
  const float* Wl = W + (size_t)blockIdx.z * K * N;
  bf16* Wtl = Wt + (size_t)blockIdx.z * K * N;
  int tx = threadIdx.x & 31, ty = threadIdx.x >> 5;  // ty 0..7
#pragma unroll
  for (int r = 0; r < 4; ++r)
    t[ty + 8 * r][tx] = Wl[(size_t)(k0 + ty + 8 * r) * N + n0 + tx];
  __syncthreads();
#pragma unroll
  for (int r = 0; r < 4; ++r)
    Wtl[(size_t)(n0 + ty + 8 * r) * K + k0 + tx] = __float2bfloat16(t[tx][ty + 8 * r]);
}

// ---------------------------------------------------------------------------
// bf16 MFMA GEMM: C[M,N] = act(A[M,K] @ Bt[N,K]^T + bias[N])
// 128x128 tile, BK=32, 256 threads = 4 waves, each wave 64x64 (4x4 frags).
// mode 0: store fp32. mode 1: gelu, store bf16.   (round-3 proven config)
// ---------------------------------------------------------------------------
__global__ __launch_bounds__(256) void gemm_mfma(
    const bf16* __restrict__ A, const bf16* __restrict__ Bt,
    const float* __restrict__ bias, void* __restrict__ Cout,
    int M, int N, int K, int mode)
{
  __shared__ short Al[128 * 32];   // [m][k], k contiguous (8 KB)
  __shared__ short Bl[128 * 32];   // [n][k], k contiguous (8 KB)
  int tid = threadIdx.x;
  int lane = tid & 63, w = tid >> 6;
  int row0 = blockIdx.y * 128, col0 = blockIdx.x * 128;
  int wm = (w >> 1) * 64, wn = (w & 1) * 64;
  int quad = lane >> 4, l16 = lane & 15;
  float4v acc[4][4] = {};

  int sr = tid >> 2;               // 0..63
  int sk = (tid & 3) * 8;          // 0,8,16,24
  const short* Ag = (const short*)A + (size_t)(row0 + sr) * K + sk;
  const short* Bg = (const short*)Bt + (size_t)(col0 + sr) * K + sk;
  const size_t half = (size_t)64 * K;

  uint4 a0 = *(const uint4*)Ag;
  uint4 a1 = *(const uint4*)(Ag + half);
  uint4 b0 = *(const uint4*)Bg;
  uint4 b1 = *(const uint4*)(Bg + half);

  const int kr = K >> 5;
  for (int kt = 0; kt < kr; ++kt) {
    __syncthreads();               // previous compute done
    *(uint4*)&Al[sr * 32 + sk]        = a0;
    *(uint4*)&Al[(sr + 64) * 32 + sk] = a1;
    *(uint4*)&Bl[sr * 32 + sk]        = b0;
    *(uint4*)&Bl[(sr + 64) * 32 + sk] = b1;
    __syncthreads();
    if (kt + 1 < kr) {             // prefetch next tile (overlaps compute)
      const short* An = Ag + (kt + 1) * 32;
      const short* Bn = Bg + (kt + 1) * 32;
      a0 = *(const uint4*)An;
      a1 = *(const uint4*)(An + half);
      b0 = *(const uint4*)Bn;
      b1 = *(const uint4*)(Bn + half);
    }
    short8 af[4], bfr[4];
#pragma unroll
    for (int mi = 0; mi < 4; ++mi)
      af[mi] = *(const short8*)&Al[(wm + mi * 16 + l16) * 32 + quad * 8];
#pragma unroll
    for (int ni = 0; ni < 4; ++ni)
      bfr[ni] = *(const short8*)&Bl[(wn + ni * 16 + l16) * 32 + quad * 8];
#pragma unroll
    for (int mi = 0; mi < 4; ++mi)
#pragma unroll
      for (int ni = 0; ni < 4; ++ni)
        acc[mi][ni] = __builtin_amdgcn_mfma_f32_16x16x32_bf16(
            af[mi], bfr[ni], acc[mi][ni], 0, 0, 0);
  }

#pragma unroll
  for (int mi = 0; mi < 4; ++mi) {
#pragma unroll
    for (int ni = 0; ni < 4; ++ni) {
      int j = col0 + wn + ni * 16 + l16;
      float bj = bias[j];
#pragma unroll
      for (int r = 0; r < 4; ++r) {
        int i = row0 + wm + mi * 16 + quad * 4 + r;
        float v = acc[mi][ni][r] + bj;
        if (mode == 1) {
          v = 0.5f * v * (1.0f + erff(v * 0.7071067811865475f));
          ((bf16*)Cout)[(size_t)i * N + j] = __float2bfloat16(v);
        } else {
          ((float*)Cout)[(size_t)i * N + j] = v;
        }
      }
    }
  }
}

// ---------------------------------------------------------------------------
// Split-K bf16 MFMA GEMM: P[s][M][N] = A[M, s*KS:(s+1)*KS] @ Bt^T slice.
// Same 128x128/BK32 inner structure; s = blockIdx.z. No bias/act.
// ---------------------------------------------------------------------------
__global__ __launch_bounds__(256) void gemm_splitk(
    const bf16* __restrict__ A, const bf16* __restrict__ Bt,
    float* __restrict__ P, int M, int N, int K, int KS)
{
  __shared__ short Al[128 * 32];
  __shared__ short Bl[128 * 32];
  int tid = threadIdx.x;
  int lane = tid & 63, w = tid >> 6;
  int row0 = blockIdx.y * 128, col0 = blockIdx.x * 128;
  int s = blockIdx.z;
  int wm = (w >> 1) * 64, wn = (w & 1) * 64;
  int quad = lane >> 4, l16 = lane & 15;
  float4v acc[4][4] = {};

  int sr = tid >> 2;
  int sk = (tid & 3) * 8;
  const short* Ag = (const short*)A + (size_t)(row0 + sr) * K + s * KS + sk;
  const short* Bg = (const short*)Bt + (size_t)(col0 + sr) * K + s * KS + sk;
  const size_t half = (size_t)64 * K;

  uint4 a0 = *(const uint4*)Ag;
  uint4 a1 = *(const uint4*)(Ag + half);
  uint4 b0 = *(const uint4*)Bg;
  uint4 b1 = *(const uint4*)(Bg + half);

  const int kr = KS >> 5;
  for (int kt = 0; kt < kr; ++kt) {
    __syncthreads();
    *(uint4*)&Al[sr * 32 + sk]        = a0;
    *(uint4*)&Al[(sr + 64) * 32 + sk] = a1;
    *(uint4*)&Bl[sr * 32 + sk]        = b0;
    *(uint4*)&Bl[(sr + 64) * 32 + sk] = b1;
    __syncthreads();
    if (kt + 1 < kr) {
      const short* An = Ag + (kt + 1) * 32;
      const short* Bn = Bg + (kt + 1) * 32;
      a0 = *(const uint4*)An;
      a1 = *(const uint4*)(An + half);
      b0 = *(const uint4*)Bn;
      b1 = *(const uint4*)(Bn + half);
    }
    short8 af[4], bfr[4];
#pragma unroll
    for (int mi = 0; mi < 4; ++mi)
      af[mi] = *(const short8*)&Al[(wm + mi * 16 + l16) * 32 + quad * 8];
#pragma unroll
    for (int ni = 0; ni < 4; ++ni)
      bfr[ni] = *(const short8*)&Bl[(wn + ni * 16 + l16) * 32 + quad * 8];
#pragma unroll
    for (int mi = 0; mi < 4; ++mi)
#pragma unroll
      for (int ni = 0; ni < 4; ++ni)
        acc[mi][ni] = __builtin_amdgcn_mfma_f32_16x16x32_bf16(
            af[mi], bfr[ni], acc[mi][ni], 0, 0, 0);
  }

  float* Ps = P + (size_t)s * M * N;
#pragma unroll
  for (int mi = 0; mi < 4; ++mi) {
#pragma unroll
    for (int ni = 0; ni < 4; ++ni) {
      int j = col0 + wn + ni * 16 + l16;
#pragma unroll
      for (int r = 0; r < 4; ++r) {
        int i = row0 + wm + mi * 16 + quad * 4 + r;
        Ps[(size_t)i * N + j] = acc[mi][ni][r];
      }
    }
  }
}

// ---------------------------------------------------------------------------
// C[idx..idx+3] = bias + sum over 4 split partials (float4 vectorized)
// ---------------------------------------------------------------------------
__global__ __launch_bounds__(256) void reduce4_bias_kernel(
    const float* __restrict__ P, const float* __restrict__ bias,
    float* __restrict__ C, int MN, int N)
{
  int idx = (blockIdx.x * 256 + threadIdx.x) * 4;
  float4 s0 = *(const float4*)&P[idx];
  float4 s1 = *(const float4*)&P[idx + MN];
  float4 s2 = *(const float4*)&P[idx + 2 * MN];
  float4 s3 = *(const float4*)&P[idx + 3 * MN];
  float4 b  = *(const float4*)&bias[idx & (N - 1)];
  float4 r;
  r.x = s0.x + s1.x + s2.x + s3.x + b.x;
  r.y = s0.y + s1.y + s2.y + s3.y + b.y;
  r.z = s0.z + s1.z + s2.z + s3.z + b.z;
  r.w = s0.w + s1.w + s2.w + s3.w + b.w;
  *(float4*)&C[idx] = r;
}

// ---------------------------------------------------------------------------
// FAVOR+ feature map (in place on [B,T,H,64] fp32)
// ---------------------------------------------------------------------------
__global__ __launch_bounds__(64) void favor_kernel(
    float* __restrict__ x, const float* __restrict__ rfs)
{
  int bth = blockIdx.x;
  int h = bth & (H_ - 1);
  int m = threadIdx.x;
  __shared__ float xp[64];
  size_t off = (size_t)bth * 64;
  xp[m] = x[off + m] * 0.35355339059327373f;   // 64^-0.25
  __syncthreads();
  const float* R = rfs + h * 64 * 64;
  float sq = 0.f, dot = 0.f;
#pragma unroll 8
  for (int dd = 0; dd < 64; ++dd) {
    float xv = xp[dd];
    sq  += xv * xv;
    dot += xv * R[dd * 64 + m];
  }
  x[off + m] = __expf(dot - 0.5f * sq);
}

// ---------------------------------------------------------------------------
// Pass 1: per-chunk sums (chunks 0..30 per bh)
// ---------------------------------------------------------------------------
__global__ __launch_bounds__(256) void chunk_sum_kernel(
    const float* __restrict__ kf, const float* __restrict__ v,
    float* __restrict__ buf)
{
  int bh = blockIdx.x / 31;
  int c  = blockIdx.x % 31;
  int b = bh >> 3, h = bh & 7;
  __shared__ float Ks[64][68], Vs[64][68];
  int tid = threadIdx.x;
  int d = tid & 63, g = tid >> 6;
  for (int t4 = 0; t4 < 64; t4 += 4) {
    int t = t4 + g;
    size_t off = ((size_t)(b * T_ + c * 64 + t) * D_) + h * 64 + d;
    Ks[t][d] = kf[off];
    Vs[t][d] = v[off];
  }
  __syncthreads();
  float acc[16];
#pragma unroll
  for (int i = 0; i < 16; ++i) acc[i] = 0.f;
  for (int t = 0; t < 64; ++t) {
    float vv = Vs[t][d];
#pragma unroll
    for (int i = 0; i < 16; ++i) acc[i] += Ks[t][g * 16 + i] * vv;
  }
  size_t bo = (size_t)(bh * 31 + c) * CENT_;
#pragma unroll
  for (int i = 0; i < 16; ++i) buf[bo + (size_t)(g * 16 + i) * 64 + d] = acc[i];
  if (tid < 64) {
    float zz = 0.f;
    for (int t = 0; t < 64; ++t) zz += Ks[t][tid];
    buf[bo + 4096 + tid] = zz;
  }
}

// ---------------------------------------------------------------------------
// Pass 2: inclusive scan over 31 chunk states per (b,h)
// ---------------------------------------------------------------------------
__global__ __launch_bounds__(256) void chunk_prefix_kernel(float* __restrict__ buf)
{
  int bh = blockIdx.x / 17;
  int grp = blockIdx.x % 17;
  int e = grp * 256 + threadIdx.x;
  if (e >= CENT_) return;
  size_t base = (size_t)bh * 31 * CENT_ + e;
  float run = 0.f;
  for (int c = 0; c < 31; ++c) {
    run += buf[base + (size_t)c * CENT_];
    buf[base + (size_t)c * CENT_] = run;
  }
}

// ---------------------------------------------------------------------------
// Pass 3: per-chunk attention. Pad 65: Qs[i=lane][m] bank=(i+m)%32 -> 2-way
// (stride 68 was (4i+m)%32 = 8-way conflict).
// ---------------------------------------------------------------------------
__global__ __launch_bounds__(256) void chunk_attn_kernel(
    const float* __restrict__ qf, const float* __restrict__ kf,
    const float* __restrict__ v, const float* __restrict__ buf,
    float* __restrict__ out)
{
  int bh = blockIdx.x >> 5;
  int c  = blockIdx.x & 31;
  int b = bh >> 3, h = bh & 7;
  __shared__ float Qs[64][65], Ks[64][65], Vs[64][65];  // Ks reused for A
  __shared__ float den[64];
  int tid = threadIdx.x;
  int d = tid & 63, g = tid >> 6;
  for (int t4 = 0; t4 < 64; t4 += 4) {
    int t = t4 + g;
    size_t off = ((size_t)(b * T_ + c * 64 + t) * D_) + h * 64 + d;
    Qs[t][d] = qf[off];
    Ks[t][d] = kf[off];
    Vs[t][d] = v[off];
  }
  __syncthreads();
  float a[16];
  {
    int i = d;
#pragma unroll
    for (int jj = 0; jj < 16; ++jj) a[jj] = 0.f;
    for (int m = 0; m < 64; ++m) {
      float qv = Qs[i][m];
#pragma unroll
      for (int jj = 0; jj < 16; ++jj) a[jj] += qv * Ks[g * 16 + jj][m];
    }
  }
  __syncthreads();
  {
    int i = d;
#pragma unroll
    for (int jj = 0; jj < 16; ++jj) {
      int j = g * 16 + jj;
      Ks[i][j] = (j <= i) ? a[jj] : 0.f;
    }
  }
  __syncthreads();
  const float* S0 = buf + (size_t)(bh * 31 + (c - 1)) * CENT_;  // valid if c>0
  if (tid < 64) {
    int i = tid;
    float dn = 0.f;
    for (int j = 0; j < 64; ++j) dn += Ks[i][j];
    if (c > 0) {
      const float* z0 = S0 + 4096;
      for (int m = 0; m < 64; ++m) dn += Qs[i][m] * z0[m];
    }
    den[i] = dn;
  }
  float acc[16];
#pragma unroll
  for (int ii = 0; ii < 16; ++ii) acc[ii] = 0.f;
  for (int j = 0; j < 64; ++j) {
    float vv = Vs[j][d];
#pragma unroll
    for (int ii = 0; ii < 16; ++ii) acc[ii] += Ks[g * 16 + ii][j] * vv;
  }
  if (c > 0) {
    for (int m = 0; m < 64; ++m) {
      float s0 = S0[(size_t)m * 64 + d];
#pragma unroll
      for (int ii = 0; ii < 16; ++ii) acc[ii] += Qs[g * 16 + ii][m] * s0;
    }
  }
  __syncthreads();
#pragma unroll
  for (int ii = 0; ii < 16; ++ii) {
    int i = g * 16 + ii;
    size_t off = ((size_t)(b * T_ + c * 64 + i) * D_) + h * 64 + d;
    out[off] = acc[ii] / (den[i] + 1e-16f);
  }
}

// ---------------------------------------------------------------------------
// x[row,:] += LayerNorm(a[row,:]) * g + b ; also writes bf16 mirror xb
// ---------------------------------------------------------------------------
__global__ __launch_bounds__(256) void ln_add_kernel(
    float* __restrict__ x, bf16* __restrict__ xb, const float* __restrict__ a,
    const float* __restrict__ g, const float* __restrict__ bta)
{
  int row = blockIdx.x;
  int tid = threadIdx.x;
  const float* ar = a + (size_t)row * D_;
  float v0 = ar[tid], v1 = ar[tid + 256];
  __shared__ float red[4];
  float w = v0 + v1;
  for (int o = 32; o > 0; o >>= 1) w += __shfl_down(w, o, 64);
  if ((tid & 63) == 0) red[tid >> 6] = w;
  __syncthreads();
  float mu = (red[0] + red[1] + red[2] + red[3]) * (1.f / 512.f);
  float d0 = v0 - mu, d1 = v1 - mu;
  __syncthreads();
  w = d0 * d0 + d1 * d1;
  for (int o = 32; o > 0; o >>= 1) w += __shfl_down(w, o, 64);
  if ((tid & 63) == 0) red[tid >> 6] = w;
  __syncthreads();
  float var = (red[0] + red[1] + red[2] + red[3]) * (1.f / 512.f);
  float rs = rsqrtf(var + 1e-5f);
  size_t xoff = (size_t)row * D_;
  float n0 = x[xoff + tid]       + d0 * rs * g[tid]       + bta[tid];
  float n1 = x[xoff + tid + 256] + d1 * rs * g[tid + 256] + bta[tid + 256];
  x[xoff + tid]        = n0;
  x[xoff + tid + 256]  = n1;
  xb[xoff + tid]       = __float2bfloat16(n0);
  xb[xoff + tid + 256] = __float2bfloat16(n1);
}

// ---------------------------------------------------------------------------
extern "C" void kernel_launch(void* const* d_in, const int* in_sizes, int n_in,
                              void* d_out, int out_size, void* d_ws, size_t ws_size,
                              hipStream_t stream) {
  const int*   tokens = (const int*)  d_in[0];
  const float* emb    = (const float*)d_in[1];
  const float* Wq     = (const float*)d_in[2];
  const float* bq     = (const float*)d_in[3];
  const float* Wk     = (const float*)d_in[4];
  const float* bk     = (const float*)d_in[5];
  const float* Wv     = (const float*)d_in[6];
  const float* bv     = (const float*)d_in[7];
  const float* rfs    = (const float*)d_in[8];
  const float* ln1g   = (const float*)d_in[9];
  const float* ln1b   = (const float*)d_in[10];
  const float* ln2g   = (const float*)d_in[11];
  const float* ln2b   = (const float*)d_in[12];
  const float* WU     = (const float*)d_in[13];
  const float* bU     = (const float*)d_in[14];
  const float* WV     = (const float*)d_in[15];
  const float* bV     = (const float*)d_in[16];
  const float* Wout   = (const float*)d_in[17];
  const float* bout   = (const float*)d_in[18];
  float* out = (float*)d_out;

  const size_t R = (size_t)BT_ * D_;          // 2,097,152 floats (8 MB)
  float* ws = (float*)d_ws;
  float* x  = ws + 0 * R;
  float* ab = ws + 1 * R;
  float* qb = ws + 2 * R;
  float* kb = ws + 3 * R;
  float* vb = ws + 4 * R;
  float* sb = ws + 5 * R;                     // chunk states (7.9 MB)
  bf16*  xb = (bf16*)(ws + 6 * R);            // R bf16 = 4 MB
  bf16*  hb = (bf16*)qb;                      // FFN hidden bf16 aliases qb+kb
  float* pb = ws + 16 * R;                    // split-K partials (<=32 MB)
  // transposed bf16 weights
  bf16* wT    = (bf16*)(ws + 6 * R + R / 2);
  bf16* WqT   = wT;                            // [L][D][D]
  bf16* WkT   = WqT + (size_t)2 * D_ * D_;
  bf16* WvT   = WkT + (size_t)2 * D_ * D_;
  bf16* WUT   = WvT + (size_t)2 * D_ * D_;     // [L][FFN][D]
  bf16* WVT   = WUT + (size_t)2 * D_ * FFN_;   // [L][D][FFN]
  bf16* WoutT = WVT + (size_t)2 * D_ * FFN_;   // [VOCAB][D]

  // ---- weight transpose-casts ----
  transpose_cast_kernel<<<dim3(D_/32,  D_/32,  2), 256, 0, stream>>>(Wq,   WqT,   D_,   D_);
  transpose_cast_kernel<<<dim3(D_/32,  D_/32,  2), 256, 0, stream>>>(Wk,   WkT,   D_,   D_);
  transpose_cast_kernel<<<dim3(D_/32,  D_/32,  2), 256, 0, stream>>>(Wv,   WvT,   D_,   D_);
  transpose_cast_kernel<<<dim3(FFN_/32,D_/32,  2), 256, 0, stream>>>(WU,   WUT,   D_,   FFN_);
  transpose_cast_kernel<<<dim3(D_/32,  FFN_/32,2), 256, 0, stream>>>(WV,   WVT,   FFN_, D_);
  transpose_cast_kernel<<<dim3(VOCAB_/32, D_/32,1), 256, 0, stream>>>(Wout, WoutT, D_,  VOCAB_);

  embed_pos_kernel<<<BT_, 512, 0, stream>>>(tokens, emb, x, xb);

  for (int l = 0; l < 2; ++l) {
    dim3 gq(D_ / 128, BT_ / 128);
    gemm_mfma<<<gq, 256, 0, stream>>>(xb, WqT + (size_t)l*D_*D_, bq + l*D_, qb, BT_, D_, D_, 0);
    gemm_mfma<<<gq, 256, 0, stream>>>(xb, WkT + (size_t)l*D_*D_, bk + l*D_, kb, BT_, D_, D_, 0);
    gemm_mfma<<<gq, 256, 0, stream>>>(xb, WvT + (size_t)l*D_*D_, bv + l*D_, vb, BT_, D_, D_, 0);

    const float* rfl = rfs + (size_t)l * H_ * 64 * 64;
    favor_kernel<<<BT_ * H_, 64, 0, stream>>>(qb, rfl);
    favor_kernel<<<BT_ * H_, 64, 0, stream>>>(kb, rfl);

    chunk_sum_kernel<<<16 * 31, 256, 0, stream>>>(kb, vb, sb);
    chunk_prefix_kernel<<<16 * 17, 256, 0, stream>>>(sb);
    chunk_attn_kernel<<<16 * NC_, 256, 0, stream>>>(qb, kb, vb, sb, ab);

    ln_add_kernel<<<BT_, 256, 0, stream>>>(x, xb, ab, ln1g + l*D_, ln1b + l*D_);

    dim3 gffn1(FFN_ / 128, BT_ / 128);
    gemm_mfma<<<gffn1, 256, 0, stream>>>(xb, WUT + (size_t)l*D_*FFN_, bU + l*FFN_, hb, BT_, FFN_, D_, 1);

    // FFN2 split-K: K=2048 -> 4 x 512, then reduce + bias
    gemm_splitk<<<dim3(D_/128, BT_/128, 4), 256, 0, stream>>>(
        hb, WVT + (size_t)l*FFN_*D_, pb, BT_, D_, FFN_, FFN_/4);
    reduce4_bias_kernel<<<(BT_*D_)/1024, 256, 0, stream>>>(
        pb, bV + l*D_, ab, BT_*D_, D_);

    ln_add_kernel<<<BT_, 256, 0, stream>>>(x, xb, ab, ln2g + l*D_, ln2b + l*D_);
  }

  // Wout split-K: K=512 -> 4 x 128, then reduce + bias
  gemm_splitk<<<dim3(VOCAB_/128, BT_/128, 4), 256, 0, stream>>>(
      xb, WoutT, pb, BT_, VOCAB_, D_, D_/4);
  reduce4_bias_kernel<<<(BT_*VOCAB_)/1024, 256, 0, stream>>>(
      pb, bout, out, BT_*VOCAB_, VOCAB_);
}

// Round 7
// 465.187 us; speedup vs baseline: 1.5438x; 1.1120x over previous
//
#include <hip/hip_runtime.h>
#include <hip/hip_bf16.h>
#include <math.h>

#define B_  2
#define T_  2048
#define D_  512
#define H_  8
#define HD_ 64
#define FFN_ 2048
#define VOCAB_ 256
#define BT_ (B_*T_)
#define NC_ 32            // chunks per (b,h), chunk size 64
#define CENT_ 4160        // floats per chunk state: 64*64 S + 64 z

typedef __attribute__((ext_vector_type(8))) short short8;
typedef __attribute__((ext_vector_type(4))) float float4v;
typedef __hip_bfloat16 bf16;

// async 16B/lane global->LDS DMA (wave-uniform LDS base + lane*16)
__device__ __forceinline__ void load16_lds(const void* g, void* l) {
  __builtin_amdgcn_global_load_lds(
      (const __attribute__((address_space(1))) unsigned int*)g,
      (__attribute__((address_space(3))) unsigned int*)l,
      16, 0, 0);
}

// ---------------------------------------------------------------------------
// Embedding + sinusoidal positional concat; writes fp32 x and bf16 mirror xb
// ---------------------------------------------------------------------------
__global__ __launch_bounds__(512) void embed_pos_kernel(
    const int* __restrict__ tokens, const float* __restrict__ emb,
    float* __restrict__ x, bf16* __restrict__ xb)
{
  int bt = blockIdx.x;          // b*T + t
  int t  = bt & (T_ - 1);
  int j  = threadIdx.x;
  float val;
  if (j < 256) {
    int tok = tokens[bt];
    val = emb[tok * 256 + j];
  } else {
    int jj = (j - 256) & 127;
    float f = expf(-(float)(2 * jj) * (9.210340371976184f / 256.0f));
    float arg = (float)t * f;
    val = (j < 384) ? sinf(arg) : cosf(arg);
  }
  size_t off = (size_t)bt * D_ + j;
  x[off]  = val;
  xb[off] = __float2bfloat16(val);
}

// ---------------------------------------------------------------------------
// Transpose-cast: W fp32 [K,N] (layer slice via blockIdx.z) -> Wt bf16 [N,K]
// ---------------------------------------------------------------------------
__global__ __launch_bounds__(256) void transpose_cast_kernel(
    const float* __restrict__ W, bf16* __restrict__ Wt, int K, int N)
{
  __shared__ float t[32][33];
  int n0 = blockIdx.x * 32, k0 = blockIdx.y * 32;
  const float* Wl = W + (size_t)blockIdx.z * K * N;
  bf16* Wtl = Wt + (size_t)blockIdx.z * K * N;
  int tx = threadIdx.x & 31, ty = threadIdx.x >> 5;  // ty 0..7
#pragma unroll
  for (int r = 0; r < 4; ++r)
    t[ty + 8 * r][tx] = Wl[(size_t)(k0 + ty + 8 * r) * N + n0 + tx];
  __syncthreads();
#pragma unroll
  for (int r = 0; r < 4; ++r)
    Wtl[(size_t)(n0 + ty + 8 * r) * K + k0 + tx] = __float2bfloat16(t[tx][ty + 8 * r]);
}

// ---------------------------------------------------------------------------
// MFMA GEMM core: acc += A[row0:+128, :kr*32] @ Bt[col0:+128, :kr*32]^T
// 128x128 tile, BK=32, 256 threads = 4 waves (2x2), global_load_lds staging.
// m97 2-barrier K-loop: barrier(vmcnt drain) -> ds_read frags -> barrier ->
// issue next DMA -> MFMA (overlaps DMA flight).
// strideK = row stride of A and Bt in elements.
// ---------------------------------------------------------------------------
__device__ __forceinline__ void mfma_core(
    const bf16* __restrict__ A, const bf16* __restrict__ Bt,
    int strideK, int kr, int row0, int col0, float4v acc[4][4])
{
  __shared__ short Al[128 * 32];   // [row][k], k contiguous
  __shared__ short Bl[128 * 32];
  int tid = threadIdx.x;
  int lane = tid & 63, w = tid >> 6;
  int wm = (w >> 1) * 64, wn = (w & 1) * 64;
  int quad = lane >> 4, l16 = lane & 15;

  // DMA assignment: wave w stages A rows [32w,32w+32) and B rows [32w,32w+32)
  // as 2 segments each; lane l covers row seg+ (l>>2), 16B chunk (l&3).
  int r0 = 32 * w + (lane >> 2);
  int ks = (lane & 3) * 8;                       // short offset in row
  const short* gA0 = (const short*)A + (size_t)(row0 + r0) * strideK + ks;
  const short* gA1 = gA0 + (size_t)16 * strideK;
  const short* gB0 = (const short*)Bt + (size_t)(col0 + r0) * strideK + ks;
  const short* gB1 = gB0 + (size_t)16 * strideK;
  short* lA0 = Al + (32 * w) * 32;               // + lane*16B implicit
  short* lA1 = Al + (32 * w + 16) * 32;
  short* lB0 = Bl + (32 * w) * 32;
  short* lB1 = Bl + (32 * w + 16) * 32;

  // prologue: tile 0 in flight
  load16_lds(gA0, lA0);
  load16_lds(gA1, lA1);
  load16_lds(gB0, lB0);
  load16_lds(gB1, lB1);

  for (int kt = 0; kt < kr; ++kt) {
    __syncthreads();               // drains vmcnt -> tile kt landed in LDS
    short8 af[4], bfr[4];
#pragma unroll
    for (int mi = 0; mi < 4; ++mi)
      af[mi] = *(const short8*)&Al[(wm + mi * 16 + l16) * 32 + quad * 8];
#pragma unroll
    for (int ni = 0; ni < 4; ++ni)
      bfr[ni] = *(const short8*)&Bl[(wn + ni * 16 + l16) * 32 + quad * 8];
    __syncthreads();               // frags in regs; LDS free for overwrite
    if (kt + 1 < kr) {             // next-tile DMA overlaps MFMA below
      int o = (kt + 1) * 32;
      load16_lds(gA0 + o, lA0);
      load16_lds(gA1 + o, lA1);
      load16_lds(gB0 + o, lB0);
      load16_lds(gB1 + o, lB1);
    }
#pragma unroll
    for (int mi = 0; mi < 4; ++mi)
#pragma unroll
      for (int ni = 0; ni < 4; ++ni)
        acc[mi][ni] = __builtin_amdgcn_mfma_f32_16x16x32_bf16(
            af[mi], bfr[ni], acc[mi][ni], 0, 0, 0);
  }
}

// ---------------------------------------------------------------------------
// Generic GEMM: C = act(A @ Bt^T + bias). mode 0: fp32. mode 1: gelu->bf16.
// ---------------------------------------------------------------------------
__global__ __launch_bounds__(256) void gemm_mfma(
    const bf16* __restrict__ A, const bf16* __restrict__ Bt,
    const float* __restrict__ bias, void* __restrict__ Cout,
    int M, int N, int K, int mode)
{
  int lane = threadIdx.x & 63, w = threadIdx.x >> 6;
  int wm = (w >> 1) * 64, wn = (w & 1) * 64;
  int quad = lane >> 4, l16 = lane & 15;
  int row0 = blockIdx.y * 128, col0 = blockIdx.x * 128;
  float4v acc[4][4] = {};
  mfma_core(A, Bt, K, K >> 5, row0, col0, acc);
#pragma unroll
  for (int mi = 0; mi < 4; ++mi) {
#pragma unroll
    for (int ni = 0; ni < 4; ++ni) {
      int j = col0 + wn + ni * 16 + l16;
      float bj = bias[j];
#pragma unroll
      for (int r = 0; r < 4; ++r) {
        int i = row0 + wm + mi * 16 + quad * 4 + r;
        float v = acc[mi][ni][r] + bj;
        if (mode == 1) {
          v = 0.5f * v * (1.0f + erff(v * 0.7071067811865475f));
          ((bf16*)Cout)[(size_t)i * N + j] = __float2bfloat16(v);
        } else {
          ((float*)Cout)[(size_t)i * N + j] = v;
        }
      }
    }
  }
}

// ---------------------------------------------------------------------------
// Batched QKV GEMM: blockIdx.z = {q,k,v}; weights wT[(z*2+l)*D*D], out
// qb/kb/vb = outb + z*BT*D. One launch, 384 blocks.
// ---------------------------------------------------------------------------
__global__ __launch_bounds__(256) void gemm_qkv(
    const bf16* __restrict__ A, const bf16* __restrict__ wT,
    const float* __restrict__ bq, const float* __restrict__ bk,
    const float* __restrict__ bv, float* __restrict__ outb, int l)
{
  int z = blockIdx.z;
  const bf16* Bt = wT + ((size_t)z * 2 + l) * D_ * D_;
  const float* bias = (z == 0 ? bq : (z == 1 ? bk : bv)) + l * D_;
  float* Cout = outb + (size_t)z * BT_ * D_;
  int lane = threadIdx.x & 63, w = threadIdx.x >> 6;
  int wm = (w >> 1) * 64, wn = (w & 1) * 64;
  int quad = lane >> 4, l16 = lane & 15;
  int row0 = blockIdx.y * 128, col0 = blockIdx.x * 128;
  float4v acc[4][4] = {};
  mfma_core(A, Bt, D_, D_ >> 5, row0, col0, acc);
#pragma unroll
  for (int mi = 0; mi < 4; ++mi) {
#pragma unroll
    for (int ni = 0; ni < 4; ++ni) {
      int j = col0 + wn + ni * 16 + l16;
      float bj = bias[j];
#pragma unroll
      for (int r = 0; r < 4; ++r) {
        int i = row0 + wm + mi * 16 + quad * 4 + r;
        Cout[(size_t)i * D_ + j] = acc[mi][ni][r] + bj;
      }
    }
  }
}

// ---------------------------------------------------------------------------
// Split-K GEMM: P[s][M][N] = A[:, s*KS:(s+1)*KS] @ slice. s = blockIdx.z.
// ---------------------------------------------------------------------------
__global__ __launch_bounds__(256) void gemm_splitk(
    const bf16* __restrict__ A, const bf16* __restrict__ Bt,
    float* __restrict__ P, int M, int N, int K, int KS)
{
  int s = blockIdx.z;
  int lane = threadIdx.x & 63, w = threadIdx.x >> 6;
  int wm = (w >> 1) * 64, wn = (w & 1) * 64;
  int quad = lane >> 4, l16 = lane & 15;
  int row0 = blockIdx.y * 128, col0 = blockIdx.x * 128;
  float4v acc[4][4] = {};
  mfma_core((const bf16*)((const short*)A + s * KS),
            (const bf16*)((const short*)Bt + s * KS),
            K, KS >> 5, row0, col0, acc);
  float* Ps = P + (size_t)s * M * N;
#pragma unroll
  for (int mi = 0; mi < 4; ++mi) {
#pragma unroll
    for (int ni = 0; ni < 4; ++ni) {
      int j = col0 + wn + ni * 16 + l16;
#pragma unroll
      for (int r = 0; r < 4; ++r) {
        int i = row0 + wm + mi * 16 + quad * 4 + r;
        Ps[(size_t)i * N + j] = acc[mi][ni][r];
      }
    }
  }
}

// ---------------------------------------------------------------------------
// C[idx..idx+3] = bias + sum over 4 split partials (float4 vectorized)
// ---------------------------------------------------------------------------
__global__ __launch_bounds__(256) void reduce4_bias_kernel(
    const float* __restrict__ P, const float* __restrict__ bias,
    float* __restrict__ C, int MN, int N)
{
  int idx = (blockIdx.x * 256 + threadIdx.x) * 4;
  float4 s0 = *(const float4*)&P[idx];
  float4 s1 = *(const float4*)&P[idx + MN];
  float4 s2 = *(const float4*)&P[idx + 2 * MN];
  float4 s3 = *(const float4*)&P[idx + 3 * MN];
  float4 b  = *(const float4*)&bias[idx & (N - 1)];
  float4 r;
  r.x = s0.x + s1.x + s2.x + s3.x + b.x;
  r.y = s0.y + s1.y + s2.y + s3.y + b.y;
  r.z = s0.z + s1.z + s2.z + s3.z + b.z;
  r.w = s0.w + s1.w + s2.w + s3.w + b.w;
  *(float4*)&C[idx] = r;
}

// ---------------------------------------------------------------------------
// FAVOR+ feature map, in place on qb and kb; one wave per (bth, side).
// ---------------------------------------------------------------------------
__global__ __launch_bounds__(256) void favor_kernel(
    float* __restrict__ qb, float* __restrict__ kb,
    const float* __restrict__ rfs)
{
  int wv = threadIdx.x >> 6;
  int u = blockIdx.x * 4 + wv;      // 0 .. 2*BT*H-1
  int m = threadIdx.x & 63;
  int side = u & 1;
  int bth = u >> 1;
  int h = bth & (H_ - 1);
  float* x = side ? kb : qb;
  __shared__ float xps[4][64];
  float* xp = xps[wv];
  size_t off = (size_t)bth * 64;
  xp[m] = x[off + m] * 0.35355339059327373f;   // 64^-0.25
  __syncthreads();
  const float* R = rfs + h * 64 * 64;
  float sq = 0.f, dot = 0.f;
#pragma unroll 8
  for (int dd = 0; dd < 64; ++dd) {
    float xv = xp[dd];
    sq  += xv * xv;
    dot += xv * R[dd * 64 + m];
  }
  x[off + m] = __expf(dot - 0.5f * sq);
}

// ---------------------------------------------------------------------------
// Pass 1: per-chunk sums (chunks 0..30 per bh)
// ---------------------------------------------------------------------------
__global__ __launch_bounds__(256) void chunk_sum_kernel(
    const float* __restrict__ kf, const float* __restrict__ v,
    float* __restrict__ buf)
{
  int bh = blockIdx.x / 31;
  int c  = blockIdx.x % 31;
  int b = bh >> 3, h = bh & 7;
  __shared__ float Ks[64][68], Vs[64][68];
  int tid = threadIdx.x;
  int d = tid & 63, g = tid >> 6;
  for (int t4 = 0; t4 < 64; t4 += 4) {
    int t = t4 + g;
    size_t off = ((size_t)(b * T_ + c * 64 + t) * D_) + h * 64 + d;
    Ks[t][d] = kf[off];
    Vs[t][d] = v[off];
  }
  __syncthreads();
  float acc[16];
#pragma unroll
  for (int i = 0; i < 16; ++i) acc[i] = 0.f;
  for (int t = 0; t < 64; ++t) {
    float vv = Vs[t][d];
#pragma unroll
    for (int i = 0; i < 16; ++i) acc[i] += Ks[t][g * 16 + i] * vv;
  }
  size_t bo = (size_t)(bh * 31 + c) * CENT_;
#pragma unroll
  for (int i = 0; i < 16; ++i) buf[bo + (size_t)(g * 16 + i) * 64 + d] = acc[i];
  if (tid < 64) {
    float zz = 0.f;
    for (int t = 0; t < 64; ++t) zz += Ks[t][tid];
    buf[bo + 4096 + tid] = zz;
  }
}

// ---------------------------------------------------------------------------
// Pass 2: inclusive scan over 31 chunk states per (b,h)
// ---------------------------------------------------------------------------
__global__ __launch_bounds__(256) void chunk_prefix_kernel(float* __restrict__ buf)
{
  int bh = blockIdx.x / 17;
  int grp = blockIdx.x % 17;
  int e = grp * 256 + threadIdx.x;
  if (e >= CENT_) return;
  size_t base = (size_t)bh * 31 * CENT_ + e;
  float run = 0.f;
  for (int c = 0; c < 31; ++c) {
    run += buf[base + (size_t)c * CENT_];
    buf[base + (size_t)c * CENT_] = run;
  }
}

// ---------------------------------------------------------------------------
// Pass 3: per-chunk attention (pad 65: lane-row reads 2-way, conflict-free)
// ---------------------------------------------------------------------------
__global__ __launch_bounds__(256) void chunk_attn_kernel(
    const float* __restrict__ qf, const float* __restrict__ kf,
    const float* __restrict__ v, const float* __restrict__ buf,
    float* __restrict__ out)
{
  int bh = blockIdx.x >> 5;
  int c  = blockIdx.x & 31;
  int b = bh >> 3, h = bh & 7;
  __shared__ float Qs[64][65], Ks[64][65], Vs[64][65];  // Ks reused for A
  __shared__ float den[64];
  int tid = threadIdx.x;
  int d = tid & 63, g = tid >> 6;
  for (int t4 = 0; t4 < 64; t4 += 4) {
    int t = t4 + g;
    size_t off = ((size_t)(b * T_ + c * 64 + t) * D_) + h * 64 + d;
    Qs[t][d] = qf[off];
    Ks[t][d] = kf[off];
    Vs[t][d] = v[off];
  }
  __syncthreads();
  float a[16];
  {
    int i = d;
#pragma unroll
    for (int jj = 0; jj < 16; ++jj) a[jj] = 0.f;
    for (int m = 0; m < 64; ++m) {
      float qv = Qs[i][m];
#pragma unroll
      for (int jj = 0; jj < 16; ++jj) a[jj] += qv * Ks[g * 16 + jj][m];
    }
  }
  __syncthreads();
  {
    int i = d;
#pragma unroll
    for (int jj = 0; jj < 16; ++jj) {
      int j = g * 16 + jj;
      Ks[i][j] = (j <= i) ? a[jj] : 0.f;
    }
  }
  __syncthreads();
  const float* S0 = buf + (size_t)(bh * 31 + (c - 1)) * CENT_;  // valid if c>0
  if (tid < 64) {
    int i = tid;
    float dn = 0.f;
    for (int j = 0; j < 64; ++j) dn += Ks[i][j];
    if (c > 0) {
      const float* z0 = S0 + 4096;
      for (int m = 0; m < 64; ++m) dn += Qs[i][m] * z0[m];
    }
    den[i] = dn;
  }
  float acc[16];
#pragma unroll
  for (int ii = 0; ii < 16; ++ii) acc[ii] = 0.f;
  for (int j = 0; j < 64; ++j) {
    float vv = Vs[j][d];
#pragma unroll
    for (int ii = 0; ii < 16; ++ii) acc[ii] += Ks[g * 16 + ii][j] * vv;
  }
  if (c > 0) {
    for (int m = 0; m < 64; ++m) {
      float s0 = S0[(size_t)m * 64 + d];
#pragma unroll
      for (int ii = 0; ii < 16; ++ii) acc[ii] += Qs[g * 16 + ii][m] * s0;
    }
  }
  __syncthreads();
#pragma unroll
  for (int ii = 0; ii < 16; ++ii) {
    int i = g * 16 + ii;
    size_t off = ((size_t)(b * T_ + c * 64 + i) * D_) + h * 64 + d;
    out[off] = acc[ii] / (den[i] + 1e-16f);
  }
}

// ---------------------------------------------------------------------------
// x[row,:] += LayerNorm(a[row,:]) * g + b ; also writes bf16 mirror xb
// ---------------------------------------------------------------------------
__global__ __launch_bounds__(256) void ln_add_kernel(
    float* __restrict__ x, bf16* __restrict__ xb, const float* __restrict__ a,
    const float* __restrict__ g, const float* __restrict__ bta)
{
  int row = blockIdx.x;
  int tid = threadIdx.x;
  const float* ar = a + (size_t)row * D_;
  float v0 = ar[tid], v1 = ar[tid + 256];
  __shared__ float red[4];
  float w = v0 + v1;
  for (int o = 32; o > 0; o >>= 1) w += __shfl_down(w, o, 64);
  if ((tid & 63) == 0) red[tid >> 6] = w;
  __syncthreads();
  float mu = (red[0] + red[1] + red[2] + red[3]) * (1.f / 512.f);
  float d0 = v0 - mu, d1 = v1 - mu;
  __syncthreads();
  w = d0 * d0 + d1 * d1;
  for (int o = 32; o > 0; o >>= 1) w += __shfl_down(w, o, 64);
  if ((tid & 63) == 0) red[tid >> 6] = w;
  __syncthreads();
  float var = (red[0] + red[1] + red[2] + red[3]) * (1.f / 512.f);
  float rs = rsqrtf(var + 1e-5f);
  size_t xoff = (size_t)row * D_;
  float n0 = x[xoff + tid]       + d0 * rs * g[tid]       + bta[tid];
  float n1 = x[xoff + tid + 256] + d1 * rs * g[tid + 256] + bta[tid + 256];
  x[xoff + tid]        = n0;
  x[xoff + tid + 256]  = n1;
  xb[xoff + tid]       = __float2bfloat16(n0);
  xb[xoff + tid + 256] = __float2bfloat16(n1);
}

// ---------------------------------------------------------------------------
extern "C" void kernel_launch(void* const* d_in, const int* in_sizes, int n_in,
                              void* d_out, int out_size, void* d_ws, size_t ws_size,
                              hipStream_t stream) {
  const int*   tokens = (const int*)  d_in[0];
  const float* emb    = (const float*)d_in[1];
  const float* Wq     = (const float*)d_in[2];
  const float* bq     = (const float*)d_in[3];
  const float* Wk     = (const float*)d_in[4];
  const float* bk     = (const float*)d_in[5];
  const float* Wv     = (const float*)d_in[6];
  const float* bv     = (const float*)d_in[7];
  const float* rfs    = (const float*)d_in[8];
  const float* ln1g   = (const float*)d_in[9];
  const float* ln1b   = (const float*)d_in[10];
  const float* ln2g   = (const float*)d_in[11];
  const float* ln2b   = (const float*)d_in[12];
  const float* WU     = (const float*)d_in[13];
  const float* bU     = (const float*)d_in[14];
  const float* WV     = (const float*)d_in[15];
  const float* bV     = (const float*)d_in[16];
  const float* Wout   = (const float*)d_in[17];
  const float* bout   = (const float*)d_in[18];
  float* out = (float*)d_out;

  const size_t R = (size_t)BT_ * D_;          // 2,097,152 floats (8 MB)
  float* ws = (float*)d_ws;
  float* x  = ws + 0 * R;
  float* ab = ws + 1 * R;
  float* qb = ws + 2 * R;
  float* kb = ws + 3 * R;
  float* vb = ws + 4 * R;
  float* sb = ws + 5 * R;                     // chunk states (7.9 MB)
  bf16*  xb = (bf16*)(ws + 6 * R);            // R bf16 = 4 MB
  bf16*  hb = (bf16*)qb;                      // FFN hidden bf16 aliases qb+kb
  float* pb = ws + 16 * R;                    // split-K partials (<=32 MB)
  // transposed bf16 weights
  bf16* wT    = (bf16*)(ws + 6 * R + R / 2);
  bf16* WqT   = wT;                            // [L][D][D]
  bf16* WkT   = WqT + (size_t)2 * D_ * D_;
  bf16* WvT   = WkT + (size_t)2 * D_ * D_;
  bf16* WUT   = WvT + (size_t)2 * D_ * D_;     // [L][FFN][D]
  bf16* WVT   = WUT + (size_t)2 * D_ * FFN_;   // [L][D][FFN]
  bf16* WoutT = WVT + (size_t)2 * D_ * FFN_;   // [VOCAB][D]

  // ---- weight transpose-casts ----
  transpose_cast_kernel<<<dim3(D_/32,  D_/32,  2), 256, 0, stream>>>(Wq,   WqT,   D_,   D_);
  transpose_cast_kernel<<<dim3(D_/32,  D_/32,  2), 256, 0, stream>>>(Wk,   WkT,   D_,   D_);
  transpose_cast_kernel<<<dim3(D_/32,  D_/32,  2), 256, 0, stream>>>(Wv,   WvT,   D_,   D_);
  transpose_cast_kernel<<<dim3(FFN_/32,D_/32,  2), 256, 0, stream>>>(WU,   WUT,   D_,   FFN_);
  transpose_cast_kernel<<<dim3(D_/32,  FFN_/32,2), 256, 0, stream>>>(WV,   WVT,   FFN_, D_);
  transpose_cast_kernel<<<dim3(VOCAB_/32, D_/32,1), 256, 0, stream>>>(Wout, WoutT, D_,  VOCAB_);

  embed_pos_kernel<<<BT_, 512, 0, stream>>>(tokens, emb, x, xb);

  for (int l = 0; l < 2; ++l) {
    // batched QKV: one launch, z = {q,k,v}, 384 blocks
    gemm_qkv<<<dim3(D_/128, BT_/128, 3), 256, 0, stream>>>(
        xb, wT, bq, bk, bv, qb, l);

    const float* rfl = rfs + (size_t)l * H_ * 64 * 64;
    favor_kernel<<<2 * BT_ * H_ / 4, 256, 0, stream>>>(qb, kb, rfl);

    chunk_sum_kernel<<<16 * 31, 256, 0, stream>>>(kb, vb, sb);
    chunk_prefix_kernel<<<16 * 17, 256, 0, stream>>>(sb);
    chunk_attn_kernel<<<16 * NC_, 256, 0, stream>>>(qb, kb, vb, sb, ab);

    ln_add_kernel<<<BT_, 256, 0, stream>>>(x, xb, ab, ln1g + l*D_, ln1b + l*D_);

    gemm_mfma<<<dim3(FFN_/128, BT_/128), 256, 0, stream>>>(
        xb, WUT + (size_t)l*D_*FFN_, bU + l*FFN_, hb, BT_, FFN_, D_, 1);

    // FFN2 split-K: K=2048 -> 4 x 512, then reduce + bias
    gemm_splitk<<<dim3(D_/128, BT_/128, 4), 256, 0, stream>>>(
        hb, WVT + (size_t)l*FFN_*D_, pb, BT_, D_, FFN_, FFN_/4);
    reduce4_bias_kernel<<<(BT_*D_)/1024, 256, 0, stream>>>(
        pb, bV + l*D_, ab, BT_*D_, D_);

    ln_add_kernel<<<BT_, 256, 0, stream>>>(x, xb, ab, ln2g + l*D_, ln2b + l*D_);
  }

  // Wout split-K: K=512 -> 4 x 128, then reduce + bias
  gemm_splitk<<<dim3(VOCAB_/128, BT_/128, 4), 256, 0, stream>>>(
      xb, WoutT, pb, BT_, VOCAB_, D_, D_/4);
  reduce4_bias_kernel<<<(BT_*VOCAB_)/1024, 256, 0, stream>>>(
      pb, bout, out, BT_*VOCAB_, VOCAB_);
}